// Round 3
// baseline (194.189 us; speedup 1.0000x reference)
//
#include <hip/hip_runtime.h>

// Fixed shape: B=1, H=2048, W=3072. Window WC=14, taps idx=(3,7,10).
constexpr int Wd = 3072;
constexpr int WC = 14;

// Pure streaming kernel: no LDS, no __syncthreads. Grid (3, 2048) x 256:
// thread (bx,t) handles float4-column u = bx*256+t of row h=by, i.e. the 4
// outputs at w0=4u.. per plane. Halo spans are read as ALIGNED float4s
// straight from global; L1 serves the 3x overlap between neighbors.
//   zbuf[k] = z[w0 + k - 16], k in [0,20)  (5 aligned float4: zrow4[u-4+i])
//   xbuf[k] = x[w0 + k - 12], k in [0,28)  (7 aligned float4: xrow4[u-3+i])
// Out-of-row entries are zeroed (x and z are conceptually zero-padded).
__global__ __launch_bounds__(256)
void color_restore_kernel(const float* __restrict__ xg,
                          const float* __restrict__ zg,
                          float* __restrict__ out, int Hn)
{
    const int u = blockIdx.x * 256 + threadIdx.x;  // 0..767
    const int h = blockIdx.y;
    const int w0 = 4 * u;

    const float4* xrow = (const float4*)(xg + (size_t)h * Wd);
    const float4* zrow = (const float4*)(zg + (size_t)h * Wd);
    const float4 zero4 = make_float4(0.f, 0.f, 0.f, 0.f);

    float zbuf[20];
    float4* zb = (float4*)zbuf;
    if (u >= 4) {                          // fast path: all 11 inner waves
#pragma unroll
        for (int i = 0; i < 5; ++i) zb[i] = zrow[u - 4 + i];
    } else {
#pragma unroll
        for (int i = 0; i < 5; ++i) {
            const int c = u - 4 + i;
            zb[i] = (c >= 0) ? zrow[c] : zero4;
        }
    }

    float xbuf[28];
    float4* xb = (float4*)xbuf;
    if (u >= 3 && u < 765) {               // fast path
#pragma unroll
        for (int i = 0; i < 7; ++i) xb[i] = xrow[u - 3 + i];
    } else {
#pragma unroll
        for (int i = 0; i < 7; ++i) {
            const int c = u - 3 + i;
            xb[i] = (c >= 0 && c < (Wd >> 2)) ? xrow[c] : zero4;
        }
    }

    // ---- initial 14-tap window at w = w0 ----
    float den = 0.f, n0 = 0.f, n1 = 0.f, n2 = 0.f;
#pragma unroll
    for (int s = 0; s < WC; ++s) {         // j = w0 - 13 + s
        const float zj = zbuf[3 + s];
        den += zj;
        n0 = fmaf(xbuf[s + 2], zj, n0);    // x[j+3]
        n1 = fmaf(xbuf[s + 6], zj, n1);    // x[j+7]
        n2 = fmaf(xbuf[s + 9], zj, n2);    // x[j+10]
    }

    float y0[4], y1[4], y2[4], r0[4], r1[4], r2[4];
#pragma unroll
    for (int q = 0; q < 4; ++q) {          // w = w0 + q
        if (q > 0) {
            const float zin = zbuf[16 + q];   // z[w]
            const float zot = zbuf[2 + q];    // z[w-14]
            den += zin - zot;
            n0 += xbuf[15 + q] * zin - xbuf[1 + q] * zot;  // x[w+3],  x[w-11]
            n1 += xbuf[19 + q] * zin - xbuf[5 + q] * zot;  // x[w+7],  x[w-7]
            n2 += xbuf[22 + q] * zin - xbuf[8 + q] * zot;  // x[w+10], x[w-4]
        }
        const float rinv = __builtin_amdgcn_rcpf(den);
        y0[q] = n0 * rinv;
        y1[q] = n1 * rinv;
        y2[q] = n2 * rinv;
        r0[q] = zbuf[13 + q];   // z[w-3]
        r1[q] = zbuf[9 + q];    // z[w-7]
        r2[q] = zbuf[6 + q];    // z[w-10]
    }

    // ---- coalesced float4 stores, 6 plane streams ----
    const int plane = Hn * Wd;
    float* yout = out;
    float* rout = out + 3 * (size_t)plane;
    const int off = h * Wd + w0;
    *(float4*)(yout + off)             = make_float4(y0[0], y0[1], y0[2], y0[3]);
    *(float4*)(yout + plane + off)     = make_float4(y1[0], y1[1], y1[2], y1[3]);
    *(float4*)(yout + 2 * plane + off) = make_float4(y2[0], y2[1], y2[2], y2[3]);
    *(float4*)(rout + off)             = make_float4(r0[0], r0[1], r0[2], r0[3]);
    *(float4*)(rout + plane + off)     = make_float4(r1[0], r1[1], r1[2], r1[3]);
    *(float4*)(rout + 2 * plane + off) = make_float4(r2[0], r2[1], r2[2], r2[3]);
}

extern "C" void kernel_launch(void* const* d_in, const int* in_sizes, int n_in,
                              void* d_out, int out_size, void* d_ws, size_t ws_size,
                              hipStream_t stream)
{
    const float* x = (const float*)d_in[0];
    const float* z = (const float*)d_in[1];
    float* out = (float*)d_out;
    const int Hn = in_sizes[0] / Wd;   // 2048
    color_restore_kernel<<<dim3(3, Hn), dim3(256), 0, stream>>>(x, z, out, Hn);
}